// Round 5
// baseline (331.860 us; speedup 1.0000x reference)
//
#include <hip/hip_runtime.h>

// GeneralizedRecallLoss — single fused kernel, native-trans version.
// scores (512, 8192) f32, k_vals (3,) i32, pos_num=16. Output: 1 f32 scalar.
//
// Per pair (t = (neg - pos[j] + 0.1) * 10*log2e):
//   f(d) = ln2*max(t,0) + 0.1*[t>=0] + ln2*log2(1 + 2^min(-t,10t))
// Sum of log2(1+2^a) accumulated as a product via fma(prod,u,prod); one
// v_log_f32 per (lane,j) at the end. 16 factors/lane, each in (1,2] ->
// prod <= 2^16, no overflow.
//
// KEY CHANGE vs R4: exp2f() was the OCML libm call (multi-instruction range/
// denorm fixup) — replaced by raw v_exp_f32 / v_log_f32 inline asm. Accuracy
// ~1 ulp, far inside the 1.76 output threshold.

#define ROWS 512
#define COLS 8192
#define POSN 16
#define NK 3
#define NEGF4 2044
#define BLOCK 512

typedef float f32x4 __attribute__((ext_vector_type(4)));

__device__ __forceinline__ float ex2(float x) {
    float r; asm("v_exp_f32 %0, %1" : "=v"(r) : "v"(x)); return r;
}
__device__ __forceinline__ float lg2(float x) {
    float r; asm("v_log_f32 %0, %1" : "=v"(r) : "v"(x)); return r;
}

__global__ __launch_bounds__(BLOCK, 4)
void recall_fused_kernel(const float* __restrict__ scores,
                         const int* __restrict__ k_vals,
                         float* __restrict__ out)
{
    const int row  = blockIdx.x;
    const int tid  = threadIdx.x;
    const int wave = tid >> 6;
    const int lane = tid & 63;
    const float* rowp = scores + (size_t)row * COLS;

    __shared__ float s_pos[POSN];
    __shared__ float s_part[8][POSN];

    if (tid < POSN) s_pos[tid] = rowp[tid];
    __syncthreads();

    const float C10 = 14.4269504089f;        // 10*log2(e)
    const float A0  = 1.44269504089f;        // 0.1*C10 (margin pre-folded)
    const float LN2 = 0.69314718055994531f;

    float p10[POSN];
#pragma unroll
    for (int j = 0; j < POSN; ++j) p10[j] = s_pos[j] * C10;

    float prod[POSN], accM[POSN];
    int   ncnt[POSN];
#pragma unroll
    for (int j = 0; j < POSN; ++j) { prod[j] = 1.0f; accM[j] = 0.0f; ncnt[j] = 0; }

    const f32x4* negs = reinterpret_cast<const f32x4*>(rowp + POSN);

    // all 4 nontemporal loads in flight before compute
    f32x4 v[4];
#pragma unroll
    for (int it = 0; it < 4; ++it) {
        int f = it * BLOCK + tid;
        if (it == 3 && f >= NEGF4) f = NEGF4 - 1;   // clamp addr, patch below
        v[it] = __builtin_nontemporal_load(negs + f);
    }
    if (3 * BLOCK + tid >= NEGF4) {
        v[3].x = -1.0e30f; v[3].y = -1.0e30f; v[3].z = -1.0e30f; v[3].w = -1.0e30f;
    }

#pragma unroll
    for (int it = 0; it < 4; ++it) {
        float a10[4];
        a10[0] = __fmaf_rn(v[it].x, C10, A0);
        a10[1] = __fmaf_rn(v[it].y, C10, A0);
        a10[2] = __fmaf_rn(v[it].z, C10, A0);
        a10[3] = __fmaf_rn(v[it].w, C10, A0);
#pragma unroll
        for (int e = 0; e < 4; ++e) {
#pragma unroll
            for (int j = 0; j < POSN; ++j) {
                const float t   = a10[e] - p10[j];
                const float arg = fminf(-t, 10.0f * t);       // -|scaled t|
                const float u   = ex2(arg);                   // (0,1]
                prod[j] = __fmaf_rn(prod[j], u, prod[j]);     // *= (1+u)
                accM[j] += fmaxf(t, 0.0f);
                ncnt[j] += (int)(__float_as_uint(t) >> 31);   // count t<0
            }
        }
    }

    // per-lane finish:  ln2*(accM + log2(prod)) + 0.1*(#pairs with t>=0)
#pragma unroll
    for (int j = 0; j < POSN; ++j) {
        const float nge = 16.0f - (float)ncnt[j];
        float s = __fmaf_rn(accM[j] + lg2(prod[j]), LN2, 0.1f * nge);
#pragma unroll
        for (int off = 32; off > 0; off >>= 1)
            s += __shfl_xor(s, off);
        if (lane == 0) s_part[wave][j] = s;
    }
    __syncthreads();

    if (tid < POSN) {
        const int j = tid;
        float negsum = 0.0f;
#pragma unroll
        for (int w = 0; w < 8; ++w) negsum += s_part[w][j];

        const float pj = s_pos[j];
        float cnt = -1.0f;                      // remove i==j diagonal
#pragma unroll
        for (int i = 0; i < POSN; ++i)
            cnt += (s_pos[i] >= pj) ? 1.0f : 0.0f;

        const float rank = 1.0f + cnt + negsum;

        float rsum = 0.0f;
#pragma unroll
        for (int k = 0; k < NK; ++k) {
            float z = (rank - (float)k_vals[k]) * 10.0f;
            z = fminf(z, 88.0f);
            const float e2 = ex2(-1.44269504089f * fabsf(z));
            rsum += fmaxf(z, 0.0f) + LN2 * lg2(1.0f + e2);
        }

        rsum += __shfl_xor(rsum, 8);
        rsum += __shfl_xor(rsum, 4);
        rsum += __shfl_xor(rsum, 2);
        rsum += __shfl_xor(rsum, 1);
        if (j == 0)
            atomicAdd(out, rsum * (1.0f / ((float)POSN * NK * ROWS)));
    }
}

extern "C" void kernel_launch(void* const* d_in, const int* in_sizes, int n_in,
                              void* d_out, int out_size, void* d_ws, size_t ws_size,
                              hipStream_t stream) {
    const float* scores = (const float*)d_in[0];
    const int*   k_vals = (const int*)d_in[1];
    float* out = (float*)d_out;

    hipMemsetAsync(out, 0, sizeof(float), stream);
    recall_fused_kernel<<<ROWS, BLOCK, 0, stream>>>(scores, k_vals, out);
}

// Round 6
// 83.721 us; speedup vs baseline: 3.9639x; 3.9639x over previous
//
#include <hip/hip_runtime.h>

// GeneralizedRecallLoss — two-stage, low-register-pressure, native-trans.
// scores (512, 8192) f32, k_vals (3,) i32, pos_num=16. Output: 1 f32 scalar.
//
// Stage 1 (negsum): 512 rows x 4 chunks (8 KB each, L1-resident); block=256
//   (4 waves), each wave owns 4 of the 16 j's. All 8 f4-loads issued up-front.
//   Per pair (t = (neg - pos[j] + 0.1)*10*log2e):
//     f(d) = ln2*max(t,0) + 0.1*[t>=0] + ln2*log2(1 + 2^min(-t,10t))
//   log-terms accumulated as a product (one v_log_f32 per (lane,j) at end);
//   32 factors in (1,2] -> prod <= 2^32, no overflow.
//   Trans ops via __builtin_amdgcn_exp2f/__builtin_amdgcn_logf (raw
//   v_exp_f32/v_log_f32, scheduler-visible — inline asm in R5 caused spills:
//   452 MB scratch writes).
// Stage 2 (finalize): (row,j) -> rank -> 3 recalls -> atomicAdd.

#define ROWS 512
#define COLS 8192
#define POSN 16
#define NK 3
#define NCHUNK 4
#define CHUNK_F4 511          // float4s per chunk ((8192-16)/4/4)

typedef float f32x4 __attribute__((ext_vector_type(4)));

__global__ __launch_bounds__(256, 6)
void negsum_kernel(const float* __restrict__ scores, float* __restrict__ ws)
{
    const int b     = blockIdx.x;
    const int row   = b >> 2;
    const int chunk = b & 3;
    const int wave  = threadIdx.x >> 6;
    const int lane  = threadIdx.x & 63;
    const float* rowp = scores + (size_t)row * COLS;

    const float C10 = 14.4269504089f;     // 10*log2(e)
    const float A0  = 1.44269504089f;     // 0.1*C10 (margin pre-folded)
    const float LN2 = 0.69314718055994531f;

    float p10[4];
#pragma unroll
    for (int jj = 0; jj < 4; ++jj)
        p10[jj] = rowp[wave * 4 + jj] * C10;

    const f32x4* negs =
        reinterpret_cast<const f32x4*>(rowp + POSN) + (size_t)chunk * CHUNK_F4;

    // all 8 loads in flight before compute (valid f: 0..510)
    f32x4 v[8];
#pragma unroll
    for (int it = 0; it < 8; ++it) {
        int f = it * 64 + lane;
        if (f > CHUNK_F4 - 1) f = CHUNK_F4 - 1;    // only it=7,lane=63 clamps
        v[it] = negs[f];
    }
    if (lane == 63) {                               // pad the clamped slot
        v[7].x = -1.0e30f; v[7].y = -1.0e30f; v[7].z = -1.0e30f; v[7].w = -1.0e30f;
    }

    float prod[4] = {1.f, 1.f, 1.f, 1.f};
    float accM[4] = {0.f, 0.f, 0.f, 0.f};
    int   ncnt[4] = {0, 0, 0, 0};

#pragma unroll
    for (int it = 0; it < 8; ++it) {
        float a10[4];
        a10[0] = __fmaf_rn(v[it].x, C10, A0);
        a10[1] = __fmaf_rn(v[it].y, C10, A0);
        a10[2] = __fmaf_rn(v[it].z, C10, A0);
        a10[3] = __fmaf_rn(v[it].w, C10, A0);
#pragma unroll
        for (int e = 0; e < 4; ++e) {
#pragma unroll
            for (int jj = 0; jj < 4; ++jj) {
                const float t   = a10[e] - p10[jj];
                const float arg = fminf(-t, 10.0f * t);        // -|scaled t|
                const float u   = __builtin_amdgcn_exp2f(arg); // (0,1]
                prod[jj] = __fmaf_rn(prod[jj], u, prod[jj]);   // *= (1+u)
                accM[jj] += fmaxf(t, 0.0f);
                ncnt[jj] += (int)(__float_as_uint(t) >> 31);   // count t<0
            }
        }
    }

    // negsum_partial = ln2*(accM + log2(prod)) + 0.1*(32 - ncnt)
    // (pad pairs have t=-huge: counted in ncnt, contribute 0 elsewhere)
#pragma unroll
    for (int jj = 0; jj < 4; ++jj) {
        const float nge = 32.0f - (float)ncnt[jj];
        float s = __fmaf_rn(accM[jj] + __builtin_amdgcn_logf(prod[jj]),
                            LN2, 0.1f * nge);
#pragma unroll
        for (int off = 32; off > 0; off >>= 1)
            s += __shfl_xor(s, off);
        if (lane == 0)
            ws[((size_t)(chunk * ROWS + row)) * POSN + wave * 4 + jj] = s;
    }
}

__global__ __launch_bounds__(256)
void finalize_kernel(const float* __restrict__ scores,
                     const float* __restrict__ ws,
                     const int* __restrict__ k_vals,
                     float* __restrict__ out)
{
    const int gid = blockIdx.x * 256 + threadIdx.x;   // 0..8191
    const int row = gid >> 4;
    const int j   = gid & 15;
    const float* rowp = scores + (size_t)row * COLS;

    float negsum = 0.0f;
#pragma unroll
    for (int c = 0; c < NCHUNK; ++c)
        negsum += ws[((size_t)(c * ROWS + row)) * POSN + j];

    const float pj = rowp[j];
    float cnt = -1.0f;                    // remove the i==j diagonal
#pragma unroll
    for (int i = 0; i < POSN; ++i)
        cnt += (rowp[i] >= pj) ? 1.0f : 0.0f;

    const float rank = 1.0f + cnt + negsum;

    float rsum = 0.0f;
#pragma unroll
    for (int k = 0; k < NK; ++k) {
        float z = (rank - (float)k_vals[k]) * 10.0f;
        z = fminf(z, 88.0f);
        const float e2 = __builtin_amdgcn_exp2f(-1.44269504089f * fabsf(z));
        rsum += fmaxf(z, 0.0f)
              + 0.69314718056f * __builtin_amdgcn_logf(1.0f + e2);
    }

    const int wave = threadIdx.x >> 6;
    const int lane = threadIdx.x & 63;
#pragma unroll
    for (int off = 32; off > 0; off >>= 1)
        rsum += __shfl_xor(rsum, off);

    __shared__ float sp[4];
    if (lane == 0) sp[wave] = rsum;
    __syncthreads();
    if (threadIdx.x == 0) {
        const float s = sp[0] + sp[1] + sp[2] + sp[3];
        atomicAdd(out, s * (1.0f / ((float)POSN * (float)NK * (float)ROWS)));
    }
}

extern "C" void kernel_launch(void* const* d_in, const int* in_sizes, int n_in,
                              void* d_out, int out_size, void* d_ws, size_t ws_size,
                              hipStream_t stream) {
    const float* scores = (const float*)d_in[0];
    const int*   k_vals = (const int*)d_in[1];
    float* out = (float*)d_out;
    float* ws  = (float*)d_ws;   // 4*512*16 f32 = 128 KB partial neg-sums

    hipMemsetAsync(out, 0, sizeof(float), stream);
    negsum_kernel<<<ROWS * NCHUNK, 256, 0, stream>>>(scores, ws);
    finalize_kernel<<<(ROWS * POSN) / 256, 256, 0, stream>>>(scores, ws, k_vals, out);
}